// Round 1
// baseline (507.941 us; speedup 1.0000x reference)
//
#include <hip/hip_runtime.h>
#include <hip/hip_bf16.h>
#include <stdint.h>

#define S   384
#define CM  256
#define CH  32
#define CZ  128
#define BB  256     // MSA depth b = K of GEMM1
#define EPS 1e-5f

typedef __attribute__((ext_vector_type(8))) short bf16x8;   // 8 bf16 = 4 VGPRs (guide §3)
typedef __attribute__((ext_vector_type(4))) float f32x4;

// workspace layout (bytes)
#define OFF_MNORM 0u                       // [98304][256] bf16 = 50331648
#define OFF_QT    50331648u                // [12288][256] bf16 = 6291456  (row = i*32+c, col = b)
#define OFF_KT    (OFF_QT + 6291456u)      // [12288][256] bf16            (row = j*32+d, col = b)
#define OFF_WT    (OFF_KT + 6291456u)      // [64][256] bf16 = 32768       (row c: c<32 Wq-col else Wk-col)
#define OFF_WOT   (OFF_WT + 32768u)        // [128][1024] bf16 = 262144    (WoT[e][k] = Wo[k][e])

__device__ __forceinline__ unsigned short f2bf(float x) {
  union { __hip_bfloat16 h; unsigned short u; } v;
  v.h = __float2bfloat16(x);
  return v.u;
}

// async global->LDS, 16B per lane. lds offset must be wave-uniform; HW scatters lane L to base + L*16.
__device__ __forceinline__ void gload_lds16(const void* g, char* smem, uint32_t lds_off_uniform) {
  uint32_t l32 = (uint32_t)(uintptr_t)(smem + lds_off_uniform);
  __builtin_amdgcn_global_load_lds(
      (const __attribute__((address_space(1))) uint32_t*)(uintptr_t)g,
      (__attribute__((address_space(3))) uint32_t*)(uintptr_t)l32,
      16, 0, 0);
}

// ---------------- K0: prep WT (q|k concat, transposed) and WoT (transposed), both bf16 --------------
__global__ void k0_prep(const float* __restrict__ Wq, const float* __restrict__ Wk,
                        const float* __restrict__ Wo,
                        unsigned short* __restrict__ WTg, unsigned short* __restrict__ WoTg) {
  int idx = blockIdx.x * 256 + threadIdx.x;
  if (idx < 64 * 256) {
    int c = idx >> 8, t = idx & 255;
    float v = (c < 32) ? Wq[t * 32 + c] : Wk[t * 32 + (c - 32)];
    WTg[c * 256 + t] = f2bf(v);
  }
  int j = idx - 64 * 256;
  if (j >= 0 && j < 128 * 1024) {
    int e = j >> 10, k = j & 1023;
    WoTg[e * 1024 + k] = f2bf(Wo[k * 128 + e]);
  }
}

// ---------------- K1: rmsnorm(m, g_in) -> m_norm bf16 [98304][256]; one wave per row -----------------
__global__ __launch_bounds__(256) void k1_rms(const float* __restrict__ m,
                                              const float* __restrict__ gin,
                                              unsigned short* __restrict__ mnorm) {
  int w = threadIdx.x >> 6, lane = threadIdx.x & 63;
  int row = blockIdx.x * 4 + w;
  const float4 x = *(const float4*)(m + row * 256 + lane * 4);
  float s = x.x * x.x + x.y * x.y + x.z * x.z + x.w * x.w;
  #pragma unroll
  for (int o = 32; o > 0; o >>= 1) s += __shfl_xor(s, o, 64);
  float sc = rsqrtf(s * (1.f / 256.f) + EPS);
  const float4 g = *(const float4*)(gin + lane * 4);
  union { unsigned short h[4]; uint2 u; } r;
  r.h[0] = f2bf(x.x * sc * g.x);
  r.h[1] = f2bf(x.y * sc * g.y);
  r.h[2] = f2bf(x.z * sc * g.z);
  r.h[3] = f2bf(x.w * sc * g.w);
  *(uint2*)(mnorm + row * 256 + lane * 4) = r.u;
}

// ---------------- K2: projection GEMM, writes qT/kT transposed ---------------------------------------
// C[r, c] = sum_t m_norm[grow(r)][t] * WT[c][t] + bias[c];   r = bl*4+il over (b0+bl, i0+il)
// output: qT[(i*32+c)][b], kT[(j*32+d)][b]
__global__ __launch_bounds__(256, 2) void k2_proj(const unsigned short* __restrict__ mnorm,
                                                  const unsigned short* __restrict__ WTg,
                                                  const float* __restrict__ bq,
                                                  const float* __restrict__ bk,
                                                  unsigned short* __restrict__ qT,
                                                  unsigned short* __restrict__ kT) {
  // LDS: A-tile [128][64] swz @0 (16KB) | WT [64][256] swz @16384 (32KB) | C [128][72] bf16 @49152 (18KB)
  __shared__ char smem[16384 + 32768 + 18432] __attribute__((aligned(16)));
  const int tid = threadIdx.x;
  const int w = tid >> 6, lane = tid & 63;
  const int mlo = lane & 15, quad = lane >> 4;
  const int i0 = blockIdx.x * 4, b0 = blockIdx.y * 32;

  // stage full WT once: rows of 512B, swizzle 16B-block: blk' = (t8&~7)|((t8&7)^(c&7))
  #pragma unroll
  for (int s = 0; s < 8; ++s) {
    int C0 = (w * 8 + s) * 2;
    int c = C0 + (lane >> 5);
    int j = lane & 31;
    int t8 = (j & ~7) | ((j & 7) ^ (c & 7));
    gload_lds16(WTg + c * 256 + t8 * 8, smem, 16384u + (uint32_t)C0 * 512u);
  }

  f32x4 acc[2][4];
  #pragma unroll
  for (int p = 0; p < 2; ++p)
    #pragma unroll
    for (int q = 0; q < 4; ++q) acc[p][q] = (f32x4)0.f;

  for (int kb = 0; kb < 4; ++kb) {
    __syncthreads();
    #pragma unroll
    for (int s = 0; s < 4; ++s) {
      int r = w * 32 + s * 8 + (lane >> 3);
      int grow = (b0 + (r >> 2)) * S + i0 + (r & 3);
      int k8 = (lane & 7) ^ (r & 7);
      gload_lds16(mnorm + grow * CM + kb * 64 + k8 * 8, smem, (uint32_t)(w * 32 + s * 8) * 128u);
    }
    asm volatile("s_waitcnt vmcnt(0)" ::: "memory");
    __syncthreads();
    #pragma unroll
    for (int ks = 0; ks < 2; ++ks) {
      bf16x8 af[2], bfr[4];
      int k8 = ks * 4 + quad;
      #pragma unroll
      for (int fm = 0; fm < 2; ++fm) {
        int mm = w * 32 + fm * 16 + mlo;
        af[fm] = *(const bf16x8*)(smem + mm * 128 + ((k8 ^ (mm & 7)) * 16));
      }
      #pragma unroll
      for (int fn = 0; fn < 4; ++fn) {
        int c = fn * 16 + mlo;
        int t8 = kb * 8 + ks * 4 + quad;
        bfr[fn] = *(const bf16x8*)(smem + 16384 + c * 512 + (((t8 & ~7) | ((t8 & 7) ^ (c & 7))) * 16));
      }
      #pragma unroll
      for (int fm = 0; fm < 2; ++fm)
        #pragma unroll
        for (int fn = 0; fn < 4; ++fn)
          acc[fm][fn] = __builtin_amdgcn_mfma_f32_16x16x32_bf16(af[fm], bfr[fn], acc[fm][fn], 0, 0, 0);
    }
  }
  __syncthreads();
  // C/D layout (m89): col = lane&15, row = quad*4 + reg
  unsigned short* Cl = (unsigned short*)(smem + 49152);
  #pragma unroll
  for (int fm = 0; fm < 2; ++fm)
    #pragma unroll
    for (int fn = 0; fn < 4; ++fn) {
      int cc = fn * 16 + mlo;
      float bias = (cc < 32) ? bq[cc] : bk[cc - 32];
      #pragma unroll
      for (int r = 0; r < 4; ++r) {
        int rr = w * 32 + fm * 16 + quad * 4 + r;
        Cl[rr * 72 + cc] = f2bf(acc[fm][fn][r] + bias);
      }
    }
  __syncthreads();
  // transposed writeout: thread = (il, cc); gathers 32 b-values, stores 64B
  {
    int il = tid >> 6, cc = tid & 63;
    unsigned short* dst = (cc < 32) ? (qT + ((i0 + il) * 32 + cc) * BB + b0)
                                    : (kT + ((i0 + il) * 32 + (cc - 32)) * BB + b0);
    #pragma unroll
    for (int v = 0; v < 4; ++v) {
      union { unsigned short h[8]; int4 q; } u;
      #pragma unroll
      for (int x = 0; x < 8; ++x) u.h[x] = Cl[((v * 8 + x) * 4 + il) * 72 + cc];
      *(int4*)(dst + v * 8) = u.q;
    }
  }
}

// ---------------- K3: fused  O-tile GEMM (K=b) -> @Wo + bo -> rmsnorm -> z ---------------------------
// block = (ti, tj): O-tile 128x128 over m=(iloc*32+c), n=(jloc*32+d); 4 waves in 2x2 grid, 4x4 frags.
__global__ __launch_bounds__(256, 3) void k3_fused(const unsigned short* __restrict__ qT,
                                                   const unsigned short* __restrict__ kT,
                                                   const unsigned short* __restrict__ WoT,
                                                   const float* __restrict__ bo,
                                                   const float* __restrict__ gout,
                                                   float* __restrict__ out) {
  // LDS: [0,16384) A-tile | [16384,32768) B-tile ; after GEMM1 both alias O_lds [16][1024]bf16 [0,32768)
  //      [32768,41216) zbuf [16][132] f32 | [41216,42304) red [16][17] | [42304,42368) scale[16]
  __shared__ char smem[42368] __attribute__((aligned(16)));
  const int tid = threadIdx.x;
  const int w = tid >> 6, lane = tid & 63;
  const int wm = w & 1, wn = w >> 1;
  const int ti = blockIdx.x, tj = blockIdx.y;
  const int mlo = lane & 15, quad = lane >> 4;

  f32x4 acc[4][4];
  #pragma unroll
  for (int p = 0; p < 4; ++p)
    #pragma unroll
    for (int q = 0; q < 4; ++q) acc[p][q] = (f32x4)0.f;

  // -------- GEMM1: O[m][n] = sum_b qT[ti*128+m][b] * kT[tj*128+n][b], K=256, BK=64 --------
  for (int kb = 0; kb < 4; ++kb) {
    __syncthreads();
    #pragma unroll
    for (int s = 0; s < 4; ++s) {
      int r = w * 32 + s * 8 + (lane >> 3);
      int k8 = (lane & 7) ^ (r & 7);              // source-permute => swizzled LDS, linear dest
      gload_lds16(qT + (ti * 128 + r) * BB + kb * 64 + k8 * 8, smem, (uint32_t)(w * 32 + s * 8) * 128u);
      gload_lds16(kT + (tj * 128 + r) * BB + kb * 64 + k8 * 8, smem, 16384u + (uint32_t)(w * 32 + s * 8) * 128u);
    }
    asm volatile("s_waitcnt vmcnt(0)" ::: "memory");
    __syncthreads();
    #pragma unroll
    for (int ks = 0; ks < 2; ++ks) {
      bf16x8 af[4], bfr[4];
      int k8 = ks * 4 + quad;
      #pragma unroll
      for (int f = 0; f < 4; ++f) {
        int mm = wm * 64 + f * 16 + mlo;
        af[f] = *(const bf16x8*)(smem + mm * 128 + ((k8 ^ (mm & 7)) * 16));
        int nn = wn * 64 + f * 16 + mlo;
        bfr[f] = *(const bf16x8*)(smem + 16384 + nn * 128 + ((k8 ^ (nn & 7)) * 16));
      }
      #pragma unroll
      for (int fm = 0; fm < 4; ++fm)
        #pragma unroll
        for (int fn = 0; fn < 4; ++fn)
          acc[fm][fn] = __builtin_amdgcn_mfma_f32_16x16x32_bf16(af[fm], bfr[fn], acc[fm][fn], 0, 0, 0);
    }
  }
  __syncthreads();   // everyone done reading A/B tiles; O_lds aliases them

  // -------- O (C-layout regs) -> O_lds[ij][k2] bf16, swizzled rows of 2048B --------
  #pragma unroll
  for (int fm = 0; fm < 4; ++fm)
    #pragma unroll
    for (int fn = 0; fn < 4; ++fn) {
      int col = wn * 64 + fn * 16 + mlo;
      #pragma unroll
      for (int r = 0; r < 4; ++r) {
        int row = wm * 64 + fm * 16 + quad * 4 + r;
        int ij = (row >> 5) * 4 + (col >> 5);     // iloc*4 + jloc
        int k2 = (row & 31) * 32 + (col & 31);    // c*32 + d
        int k8 = k2 >> 3;
        int off = ij * 2048 + (((k8 & ~7) | ((k8 & 7) ^ (ij & 7))) * 16) + (k2 & 7) * 2;
        *(unsigned short*)(smem + off) = f2bf(acc[fm][fn][r]);
      }
    }
  __syncthreads();

  // -------- stage 2: z[16 ij][128 e] = O @ Wo; wave w owns e in [w*32, w*32+32) --------
  // A from O_lds (shared), B streamed from global WoT (L1/L2-hot)
  f32x4 acc2[2];
  acc2[0] = (f32x4)0.f; acc2[1] = (f32x4)0.f;
  #pragma unroll 4
  for (int kk = 0; kk < 32; ++kk) {
    int k = kk * 32 + quad * 8;
    int k8 = k >> 3;
    int ij = mlo;
    bf16x8 a = *(const bf16x8*)(smem + ij * 2048 + (((k8 & ~7) | ((k8 & 7) ^ (ij & 7))) * 16));
    #pragma unroll
    for (int fn = 0; fn < 2; ++fn) {
      int e = w * 32 + fn * 16 + mlo;
      bf16x8 b = *(const bf16x8*)(WoT + e * 1024 + k);
      acc2[fn] = __builtin_amdgcn_mfma_f32_16x16x32_bf16(a, b, acc2[fn], 0, 0, 0);
    }
  }

  // -------- + bo, stash z in LDS fp32 --------
  float* zbuf = (float*)(smem + 32768);
  #pragma unroll
  for (int fn = 0; fn < 2; ++fn) {
    int e = w * 32 + fn * 16 + mlo;
    float bv = bo[e];
    #pragma unroll
    for (int r = 0; r < 4; ++r) {
      int ij = quad * 4 + r;
      zbuf[ij * 132 + e] = acc2[fn][r] + bv;
    }
  }
  __syncthreads();

  // -------- rmsnorm over e per (i,j), write out --------
  float* red = (float*)(smem + 41216);
  float* scl = (float*)(smem + 42304);
  {
    int ij = tid >> 4, part = tid & 15;
    float s = 0.f;
    #pragma unroll
    for (int u = 0; u < 8; ++u) { float v = zbuf[ij * 132 + part * 8 + u]; s += v * v; }
    red[ij * 17 + part] = s;
  }
  __syncthreads();
  if (tid < 16) {
    float s = 0.f;
    #pragma unroll
    for (int p = 0; p < 16; ++p) s += red[tid * 17 + p];
    scl[tid] = rsqrtf(s * (1.f / 128.f) + EPS);
  }
  __syncthreads();
  {
    int ij = tid >> 4, part = tid & 15;
    float sc = scl[ij];
    int gi = ti * 4 + (ij >> 2), gj = tj * 4 + (ij & 3);
    float* dst = out + ((size_t)gi * S + gj) * CZ + part * 8;
    #pragma unroll
    for (int u = 0; u < 8; ++u) {
      int e = part * 8 + u;
      dst[u] = zbuf[ij * 132 + e] * sc * gout[e];
    }
  }
}

// ---------------------------------------------------------------------------------------------------
extern "C" void kernel_launch(void* const* d_in, const int* in_sizes, int n_in,
                              void* d_out, int out_size, void* d_ws, size_t ws_size,
                              hipStream_t stream) {
  const float* m    = (const float*)d_in[0];
  const float* gin  = (const float*)d_in[1];
  const float* Wq   = (const float*)d_in[2];
  const float* bq   = (const float*)d_in[3];
  const float* Wk   = (const float*)d_in[4];
  const float* bk   = (const float*)d_in[5];
  const float* Wo   = (const float*)d_in[6];
  const float* bo   = (const float*)d_in[7];
  const float* gout = (const float*)d_in[8];

  char* ws = (char*)d_ws;
  unsigned short* mnorm = (unsigned short*)(ws + OFF_MNORM);
  unsigned short* qT    = (unsigned short*)(ws + OFF_QT);
  unsigned short* kT    = (unsigned short*)(ws + OFF_KT);
  unsigned short* WTg   = (unsigned short*)(ws + OFF_WT);
  unsigned short* WoT   = (unsigned short*)(ws + OFF_WOT);
  float* out = (float*)d_out;

  hipLaunchKernelGGL(k0_prep, dim3(576), dim3(256), 0, stream, Wq, Wk, Wo, WTg, WoT);
  hipLaunchKernelGGL(k1_rms, dim3(24576), dim3(256), 0, stream, m, gin, mnorm);
  hipLaunchKernelGGL(k2_proj, dim3(96, 8), dim3(256), 0, stream, mnorm, WTg, bq, bk, qT, kT);
  hipLaunchKernelGGL(k3_fused, dim3(96, 96), dim3(256), 0, stream, qT, kT, WoT, bo, gout, out);
}

// Round 2
// 491.502 us; speedup vs baseline: 1.0334x; 1.0334x over previous
//
#include <hip/hip_runtime.h>
#include <hip/hip_bf16.h>
#include <stdint.h>

#define S   384
#define CM  256
#define CH  32
#define CZ  128
#define BB  256     // MSA depth b = K of GEMM1
#define EPS 1e-5f

typedef __attribute__((ext_vector_type(8))) short bf16x8;   // 8 bf16 = 4 VGPRs
typedef __attribute__((ext_vector_type(4))) float f32x4;

// workspace layout (bytes)
#define OFF_MNORM 0u                       // [98304][256] bf16 = 50331648
#define OFF_QT    50331648u                // [12288][256] bf16 = 6291456  (row = i*32+c, col = b)
#define OFF_KT    (OFF_QT + 6291456u)      // [12288][256] bf16            (row = j*32+d, col = b)
#define OFF_WT    (OFF_KT + 6291456u)      // [64][256] bf16 = 32768       (row c: c<32 Wq-col else Wk-col)
#define OFF_WOT   (OFF_WT + 32768u)        // [128][1024] bf16 = 262144    WoTp[e][d*32+c] = Wo[c*32+d][e]

__device__ __forceinline__ unsigned short f2bf(float x) {
  union { __hip_bfloat16 h; unsigned short u; } v;
  v.h = __float2bfloat16(x);
  return v.u;
}

// async global->LDS, 16B per lane. lds offset must be wave-uniform; HW scatters lane L to base + L*16.
__device__ __forceinline__ void gload_lds16(const void* g, char* smem, uint32_t lds_off_uniform) {
  uint32_t l32 = (uint32_t)(uintptr_t)(smem + lds_off_uniform);
  __builtin_amdgcn_global_load_lds(
      (const __attribute__((address_space(1))) uint32_t*)(uintptr_t)g,
      (__attribute__((address_space(3))) uint32_t*)(uintptr_t)l32,
      16, 0, 0);
}

// ---------------- K0: prep WT (q|k concat, transposed) and WoTp (transposed + k-reordered) ----------
__global__ void k0_prep(const float* __restrict__ Wq, const float* __restrict__ Wk,
                        const float* __restrict__ Wo,
                        unsigned short* __restrict__ WTg, unsigned short* __restrict__ WoTg) {
  int idx = blockIdx.x * 256 + threadIdx.x;
  if (idx < 64 * 256) {
    int c = idx >> 8, t = idx & 255;
    float v = (c < 32) ? Wq[t * 32 + c] : Wk[t * 32 + (c - 32)];
    WTg[c * 256 + t] = f2bf(v);
  }
  int j = idx - 64 * 256;
  if (j >= 0 && j < 128 * 1024) {
    int e = j >> 10, dc = j & 1023;       // dc = d*32 + c  (stage-2 k order)
    int c = dc & 31, d = dc >> 5;
    WoTg[e * 1024 + dc] = f2bf(Wo[(c * 32 + d) * 128 + e]);
  }
}

// ---------------- K1: rmsnorm(m, g_in) -> m_norm bf16 [98304][256]; one wave per row -----------------
__global__ __launch_bounds__(256) void k1_rms(const float* __restrict__ m,
                                              const float* __restrict__ gin,
                                              unsigned short* __restrict__ mnorm) {
  int w = threadIdx.x >> 6, lane = threadIdx.x & 63;
  int row = blockIdx.x * 4 + w;
  const float4 x = *(const float4*)(m + row * 256 + lane * 4);
  float s = x.x * x.x + x.y * x.y + x.z * x.z + x.w * x.w;
  #pragma unroll
  for (int o = 32; o > 0; o >>= 1) s += __shfl_xor(s, o, 64);
  float sc = rsqrtf(s * (1.f / 256.f) + EPS);
  const float4 g = *(const float4*)(gin + lane * 4);
  union { unsigned short h[4]; uint2 u; } r;
  r.h[0] = f2bf(x.x * sc * g.x);
  r.h[1] = f2bf(x.y * sc * g.y);
  r.h[2] = f2bf(x.z * sc * g.z);
  r.h[3] = f2bf(x.w * sc * g.w);
  *(uint2*)(mnorm + row * 256 + lane * 4) = r.u;
}

// ---------------- K2: projection GEMM, writes qT/kT transposed ---------------------------------------
__global__ __launch_bounds__(256, 2) void k2_proj(const unsigned short* __restrict__ mnorm,
                                                  const unsigned short* __restrict__ WTg,
                                                  const float* __restrict__ bq,
                                                  const float* __restrict__ bk,
                                                  unsigned short* __restrict__ qT,
                                                  unsigned short* __restrict__ kT) {
  // LDS: A-tile [128][64] swz @0 (16KB) | WT [64][256] swz @16384 (32KB) | C [128][72] bf16 @49152 (18KB)
  __shared__ char smem[16384 + 32768 + 18432] __attribute__((aligned(16)));
  const int tid = threadIdx.x;
  const int w = tid >> 6, lane = tid & 63;
  const int mlo = lane & 15, quad = lane >> 4;
  const int i0 = blockIdx.x * 4, b0 = blockIdx.y * 32;

  #pragma unroll
  for (int s = 0; s < 8; ++s) {
    int C0 = (w * 8 + s) * 2;
    int c = C0 + (lane >> 5);
    int j = lane & 31;
    int t8 = (j & ~7) | ((j & 7) ^ (c & 7));
    gload_lds16(WTg + c * 256 + t8 * 8, smem, 16384u + (uint32_t)C0 * 512u);
  }

  f32x4 acc[2][4];
  #pragma unroll
  for (int p = 0; p < 2; ++p)
    #pragma unroll
    for (int q = 0; q < 4; ++q) acc[p][q] = (f32x4)0.f;

  for (int kb = 0; kb < 4; ++kb) {
    __syncthreads();
    #pragma unroll
    for (int s = 0; s < 4; ++s) {
      int r = w * 32 + s * 8 + (lane >> 3);
      int grow = (b0 + (r >> 2)) * S + i0 + (r & 3);
      int k8 = (lane & 7) ^ (r & 7);
      gload_lds16(mnorm + grow * CM + kb * 64 + k8 * 8, smem, (uint32_t)(w * 32 + s * 8) * 128u);
    }
    asm volatile("s_waitcnt vmcnt(0)" ::: "memory");
    __syncthreads();
    #pragma unroll
    for (int ks = 0; ks < 2; ++ks) {
      bf16x8 af[2], bfr[4];
      int k8 = ks * 4 + quad;
      #pragma unroll
      for (int fm = 0; fm < 2; ++fm) {
        int mm = w * 32 + fm * 16 + mlo;
        af[fm] = *(const bf16x8*)(smem + mm * 128 + ((k8 ^ (mm & 7)) * 16));
      }
      #pragma unroll
      for (int fn = 0; fn < 4; ++fn) {
        int c = fn * 16 + mlo;
        int t8 = kb * 8 + ks * 4 + quad;
        bfr[fn] = *(const bf16x8*)(smem + 16384 + c * 512 + (((t8 & ~7) | ((t8 & 7) ^ (c & 7))) * 16));
      }
      #pragma unroll
      for (int fm = 0; fm < 2; ++fm)
        #pragma unroll
        for (int fn = 0; fn < 4; ++fn)
          acc[fm][fn] = __builtin_amdgcn_mfma_f32_16x16x32_bf16(af[fm], bfr[fn], acc[fm][fn], 0, 0, 0);
    }
  }
  __syncthreads();
  unsigned short* Cl = (unsigned short*)(smem + 49152);
  #pragma unroll
  for (int fm = 0; fm < 2; ++fm)
    #pragma unroll
    for (int fn = 0; fn < 4; ++fn) {
      int cc = fn * 16 + mlo;
      float bias = (cc < 32) ? bq[cc] : bk[cc - 32];
      #pragma unroll
      for (int r = 0; r < 4; ++r) {
        int rr = w * 32 + fm * 16 + quad * 4 + r;
        Cl[rr * 72 + cc] = f2bf(acc[fm][fn][r] + bias);
      }
    }
  __syncthreads();
  {
    int il = tid >> 6, cc = tid & 63;
    unsigned short* dst = (cc < 32) ? (qT + ((i0 + il) * 32 + cc) * BB + b0)
                                    : (kT + ((i0 + il) * 32 + (cc - 32)) * BB + b0);
    #pragma unroll
    for (int v = 0; v < 4; ++v) {
      union { unsigned short h[8]; int4 q; } u;
      #pragma unroll
      for (int x = 0; x < 8; ++x) u.h[x] = Cl[((v * 8 + x) * 4 + il) * 72 + cc];
      *(int4*)(dst + v * 8) = u.q;
    }
  }
}

// ---------------- K3: fused  O-tile GEMM (K=b) -> @Wo + bo -> rmsnorm -> z ---------------------------
// 512 threads = 8 waves in 2x4 (wm x wn) grid; wave sub-tile 64x32, frags 4x2. acc = 32 regs/lane.
__global__ __launch_bounds__(512, 6) void k3_fused(const unsigned short* __restrict__ qT,
                                                   const unsigned short* __restrict__ kT,
                                                   const unsigned short* __restrict__ WoTp,
                                                   const float* __restrict__ bo,
                                                   const float* __restrict__ gout,
                                                   float* __restrict__ out) {
  // LDS 32KB total: [0,16384) A-tile [128][64] swz | [16384,32768) B-tile [128][64] swz
  // after GEMM1 both alias O_lds [16 ij][1024 k2'] bf16 (k2' = d*32+c), swizzled 16B blocks
  // after stage-2 MFMA, first 576B alias red[16][8] f32 + scl[16]
  __shared__ char smem[32768] __attribute__((aligned(16)));
  const int tid = threadIdx.x;
  const int w = tid >> 6, lane = tid & 63;
  const int wm = w & 1, wn = w >> 1;          // wave grid 2 (m) x 4 (n)
  const int ti = blockIdx.x, tj = blockIdx.y;
  const int mlo = lane & 15, quad = lane >> 4;

  f32x4 acc[4][2];
  #pragma unroll
  for (int p = 0; p < 4; ++p)
    #pragma unroll
    for (int q = 0; q < 2; ++q) acc[p][q] = (f32x4)0.f;

  // -------- GEMM1: O[m][n] = sum_b qT[ti*128+m][b] * kT[tj*128+n][b], K=256, BK=64 --------
  for (int kb = 0; kb < 4; ++kb) {
    __syncthreads();
    #pragma unroll
    for (int s = 0; s < 2; ++s) {
      int r = s * 64 + w * 8 + (lane >> 3);
      int k8 = (lane & 7) ^ (r & 7);          // source-permute => swizzled LDS, linear dest
      gload_lds16(qT + (ti * 128 + r) * BB + kb * 64 + k8 * 8, smem, (uint32_t)(s * 64 + w * 8) * 128u);
      gload_lds16(kT + (tj * 128 + r) * BB + kb * 64 + k8 * 8, smem, 16384u + (uint32_t)(s * 64 + w * 8) * 128u);
    }
    asm volatile("s_waitcnt vmcnt(0)" ::: "memory");
    __syncthreads();
    #pragma unroll
    for (int ks = 0; ks < 2; ++ks) {
      bf16x8 af[4], bfr[2];
      int k8 = ks * 4 + quad;
      #pragma unroll
      for (int f = 0; f < 4; ++f) {
        int mm = wm * 64 + f * 16 + mlo;
        af[f] = *(const bf16x8*)(smem + mm * 128 + ((k8 ^ (mm & 7)) * 16));
      }
      #pragma unroll
      for (int f = 0; f < 2; ++f) {
        int nn = wn * 32 + f * 16 + mlo;
        bfr[f] = *(const bf16x8*)(smem + 16384 + nn * 128 + ((k8 ^ (nn & 7)) * 16));
      }
      #pragma unroll
      for (int fm = 0; fm < 4; ++fm)
        #pragma unroll
        for (int fn = 0; fn < 2; ++fn)
          acc[fm][fn] = __builtin_amdgcn_mfma_f32_16x16x32_bf16(af[fm], bfr[fn], acc[fm][fn], 0, 0, 0);
    }
  }
  __syncthreads();   // A/B tiles consumed; O_lds aliases them

  // -------- O (C-layout regs) -> O_lds[ij][k2'] bf16, k2' = d*32 + c; packed 8B writes --------
  #pragma unroll
  for (int fm = 0; fm < 4; ++fm)
    #pragma unroll
    for (int fn = 0; fn < 2; ++fn) {
      int col = wn * 32 + fn * 16 + mlo;                 // n = jloc*32 + d
      int row0 = wm * 64 + fm * 16 + quad * 4;           // m = iloc*32 + c (r=0..3 contiguous in c)
      int ij = (wm * 2 + (fm >> 1)) * 4 + wn;            // iloc*4 + jloc
      int k20 = (col & 31) * 32 + (row0 & 31);           // d*32 + c
      int blk = k20 >> 3;
      int off = ij * 2048 + (((blk & ~7) | ((blk & 7) ^ (ij & 7))) * 16) + (k20 & 7) * 2;
      union { unsigned short h[4]; uint2 u; } pk;
      #pragma unroll
      for (int r = 0; r < 4; ++r) pk.h[r] = f2bf(acc[fm][fn][r]);
      *(uint2*)(smem + off) = pk.u;
    }
  __syncthreads();

  // -------- stage 2: z[16 ij][128 e] = O @ Wo; wave w owns e in [w*16, w*16+16) --------
  const int e = w * 16 + mlo;
  const unsigned short* wrow = WoTp + (size_t)e * 1024;
  f32x4 acc2[2];
  acc2[0] = (f32x4)0.f; acc2[1] = (f32x4)0.f;
  #pragma unroll 4
  for (int kk = 0; kk < 32; ++kk) {
    int k = kk * 32 + quad * 8;
    int blk = kk * 4 + quad;
    bf16x8 a = *(const bf16x8*)(smem + mlo * 2048 + (((blk & ~7) | ((blk & 7) ^ (mlo & 7))) * 16));
    bf16x8 b = *(const bf16x8*)(wrow + k);
    acc2[kk & 1] = __builtin_amdgcn_mfma_f32_16x16x32_bf16(a, b, acc2[kk & 1], 0, 0, 0);
  }

  // -------- + bo, rmsnorm over e per (i,j) via in-register reduction, write out --------
  float bv = bo[e], gv = gout[e];
  float v[4], sq[4];
  #pragma unroll
  for (int r = 0; r < 4; ++r) {
    v[r] = acc2[0][r] + acc2[1][r] + bv;
    sq[r] = v[r] * v[r];
  }
  // butterfly over the 16 e-lanes (mlo) within each quad: offsets 1,2,4,8 stay inside the quad
  #pragma unroll
  for (int o = 1; o < 16; o <<= 1)
    #pragma unroll
    for (int r = 0; r < 4; ++r) sq[r] += __shfl_xor(sq[r], o, 64);

  __syncthreads();                       // all O_lds reads done; red/scl alias smem
  float* red = (float*)smem;             // [16 ij][8 wave]
  float* scl = (float*)(smem + 512);     // [16]
  if (mlo == 0) {
    #pragma unroll
    for (int r = 0; r < 4; ++r) red[(quad * 4 + r) * 8 + w] = sq[r];
  }
  __syncthreads();
  if (tid < 16) {
    float s = 0.f;
    #pragma unroll
    for (int p = 0; p < 8; ++p) s += red[tid * 8 + p];
    scl[tid] = rsqrtf(s * (1.f / 128.f) + EPS);
  }
  __syncthreads();
  #pragma unroll
  for (int r = 0; r < 4; ++r) {
    int ij = quad * 4 + r;
    float sc = scl[ij];
    int gi = ti * 4 + (ij >> 2), gj = tj * 4 + (ij & 3);
    out[((size_t)gi * S + gj) * CZ + e] = v[r] * sc * gv;
  }
}

// ---------------------------------------------------------------------------------------------------
extern "C" void kernel_launch(void* const* d_in, const int* in_sizes, int n_in,
                              void* d_out, int out_size, void* d_ws, size_t ws_size,
                              hipStream_t stream) {
  const float* m    = (const float*)d_in[0];
  const float* gin  = (const float*)d_in[1];
  const float* Wq   = (const float*)d_in[2];
  const float* bq   = (const float*)d_in[3];
  const float* Wk   = (const float*)d_in[4];
  const float* bk   = (const float*)d_in[5];
  const float* Wo   = (const float*)d_in[6];
  const float* bo   = (const float*)d_in[7];
  const float* gout = (const float*)d_in[8];

  char* ws = (char*)d_ws;
  unsigned short* mnorm = (unsigned short*)(ws + OFF_MNORM);
  unsigned short* qT    = (unsigned short*)(ws + OFF_QT);
  unsigned short* kT    = (unsigned short*)(ws + OFF_KT);
  unsigned short* WTg   = (unsigned short*)(ws + OFF_WT);
  unsigned short* WoTp  = (unsigned short*)(ws + OFF_WOT);
  float* out = (float*)d_out;

  hipLaunchKernelGGL(k0_prep, dim3(576), dim3(256), 0, stream, Wq, Wk, Wo, WTg, WoTp);
  hipLaunchKernelGGL(k1_rms, dim3(24576), dim3(256), 0, stream, m, gin, mnorm);
  hipLaunchKernelGGL(k2_proj, dim3(96, 8), dim3(256), 0, stream, mnorm, WTg, bq, bk, qT, kT);
  hipLaunchKernelGGL(k3_fused, dim3(96, 96), dim3(512), 0, stream, qT, kT, WoTp, bo, gout, out);
}